// Round 4
// baseline (310.885 us; speedup 1.0000x reference)
//
#include <hip/hip_runtime.h>
#include <cstdint>

typedef _Float16 h1;
typedef _Float16 h4 __attribute__((ext_vector_type(4)));
typedef _Float16 h8 __attribute__((ext_vector_type(8)));
typedef float    f4 __attribute__((ext_vector_type(4)));
typedef float    f32x4 __attribute__((ext_vector_type(4)));

#define NB 4
#define SL 4096
#define DD 512
#define MM (NB*SL)   // 16384 total rows
#define SHIFT 12.0f

// ---------------- K0: convert Wq/Wk/Wv f32 -> fp16 into ws ----------------
__global__ __launch_bounds__(256) void convert_w_kernel(
    const float* __restrict__ Wq, const float* __restrict__ Wk, const float* __restrict__ Wv,
    h1* __restrict__ Wh)
{
    const int per = DD*DD/4;              // 65536 float4 per matrix
    int i = blockIdx.x * 256 + threadIdx.x;
    if (i >= 3*per) return;
    int mat = i / per;
    int j = i - mat*per;
    const float* src = (mat==0) ? Wq : (mat==1 ? Wk : Wv);
    f4 v = ((const f4*)src)[j];
    h4 hv;
    hv[0]=(h1)v[0]; hv[1]=(h1)v[1]; hv[2]=(h1)v[2]; hv[3]=(h1)v[3];
    ((h4*)(Wh + (size_t)mat*DD*DD))[j] = hv;
}

// ---------------- swizzled gload_lds staging (linear LDS dest, pre-swizzled src) ----------------
// LDS tile: 128 rows x 64 halves (16 KB) linear; (row, chunk s) holds global
// chunk s ^ (row&7), chunk = 16 B = 8 halves.
__device__ __forceinline__ void stage_tile(const h1* __restrict__ gbase,  // ptr at (tile_row0, k0)
                                           h1* lds, int w, int l)
{
    #pragma unroll
    for (int j = 0; j < 4; j++) {
        const int cc  = w*4 + j;                 // 1-KB chunk index (wave-uniform)
        const int row = cc*8 + (l >> 3);
        const int sc  = (l & 7) ^ (l >> 3);      // inverse-swizzled source chunk
        const h1* src = gbase + (size_t)row * DD + sc*8;
        void* dst = (char*)lds + cc*1024;
        __builtin_amdgcn_global_load_lds(
            (const __attribute__((address_space(1))) uint32_t*)src,
            (__attribute__((address_space(3))) uint32_t*)dst, 16, 0, 0);
    }
}

__device__ __forceinline__ h8 lds_frag(const h1* lds, int row, int lc)
{
    const int chunk = lc ^ (row & 7);
    return *(const h8*)(lds + row*64 + chunk*8);
}

// ---------------- K1: X @ W^T + b for Q,K,V ----------------
// A: f32 reg-staged + in-kernel fp16 convert (padded LDS); B: fp16 gload_lds.
__global__ __launch_bounds__(256) void proj_gemm(
    const float* __restrict__ Xq, const float* __restrict__ Xk, const float* __restrict__ Xv,
    const h1* __restrict__ Wh,
    const float* __restrict__ bq, const float* __restrict__ bk, const float* __restrict__ bv,
    h1* __restrict__ Qh, h1* __restrict__ Kh, float* __restrict__ Vout)
{
    const int prj = blockIdx.z;
    const float* __restrict__ X    = (prj==0) ? Xq : (prj==1 ? Xk : Xv);
    const h1*    __restrict__ W    = Wh + (size_t)prj * DD * DD;
    const float* __restrict__ bias = (prj==0) ? bq : (prj==1 ? bk : bv);

    const int m0 = blockIdx.y * 128;
    const int n0 = blockIdx.x * 128;

    __shared__ h1 As[128][72];   // padded: uniform-bank for b128 ops
    __shared__ h1 Bs[128*64];    // linear XOR-swizzled (gload_lds)

    const int tid  = threadIdx.x;
    const int lane = tid & 63;
    const int wid  = tid >> 6;
    const int wm = wid >> 1, wn = wid & 1;      // 2x2 wave grid, each 64x64
    const int g  = lane >> 4, c = lane & 15;
    const int r  = tid >> 1,  h = tid & 1;      // staging: row, half-of-64

    f32x4 acc[4][4];
    #pragma unroll
    for (int i = 0; i < 4; i++)
        #pragma unroll
        for (int j = 0; j < 4; j++) acc[i][j] = (f32x4){0.f, 0.f, 0.f, 0.f};

    for (int k0 = 0; k0 < DD; k0 += 64) {
        __syncthreads();
        stage_tile(W + (size_t)n0 * DD + k0, Bs, wid, lane);
        // stage A: 128 rows x 64 f32 -> fp16 (each thread: 32 floats)
        {
            const f4* src = (const f4*)(X + (size_t)(m0 + r) * DD + k0 + h*32);
            f4 a0=src[0], a1=src[1], a2=src[2], a3=src[3],
               a4=src[4], a5=src[5], a6=src[6], a7=src[7];
            h8 p0, p1, p2, p3;
            #pragma unroll
            for (int j = 0; j < 4; j++) {
                p0[j]=(h1)a0[j]; p0[4+j]=(h1)a1[j];
                p1[j]=(h1)a2[j]; p1[4+j]=(h1)a3[j];
                p2[j]=(h1)a4[j]; p2[4+j]=(h1)a5[j];
                p3[j]=(h1)a6[j]; p3[4+j]=(h1)a7[j];
            }
            *(h8*)&As[r][h*32]      = p0;
            *(h8*)&As[r][h*32 + 8]  = p1;
            *(h8*)&As[r][h*32 + 16] = p2;
            *(h8*)&As[r][h*32 + 24] = p3;
        }
        __syncthreads();

        #pragma unroll
        for (int kk = 0; kk < 2; kk++) {
            h8 af[4], bf[4];
            #pragma unroll
            for (int mf = 0; mf < 4; mf++) af[mf] = *(const h8*)&As[wm*64 + mf*16 + c][kk*32 + g*8];
            #pragma unroll
            for (int nf = 0; nf < 4; nf++) bf[nf] = lds_frag(Bs, wn*64 + nf*16 + c, kk*4 + g);
            #pragma unroll
            for (int mf = 0; mf < 4; mf++)
                #pragma unroll
                for (int nf = 0; nf < 4; nf++)
                    acc[mf][nf] = __builtin_amdgcn_mfma_f32_16x16x32_f16(af[mf], bf[nf], acc[mf][nf], 0, 0, 0);
        }
    }

    float bv4[4];
    #pragma unroll
    for (int nf = 0; nf < 4; nf++) bv4[nf] = bias[n0 + wn*64 + nf*16 + c];

    #pragma unroll
    for (int mf = 0; mf < 4; mf++) {
        #pragma unroll
        for (int i = 0; i < 4; i++) {
            const int row = m0 + wm*64 + mf*16 + g*4 + i;
            #pragma unroll
            for (int nf = 0; nf < 4; nf++) {
                const int col = n0 + wn*64 + nf*16 + c;
                float vv = acc[mf][nf][i] + bv4[nf];
                if (prj == 0)      Qh[(size_t)row*DD + col] = (h1)vv;
                else if (prj == 1) Kh[(size_t)row*DD + col] = (h1)vv;
                else               Vout[(size_t)row*DD + col] = vv;
            }
        }
    }
}

// ---------------- K2: e = exp(QK^T/sqrt(128) - 12) fp16; row partial sums ----------------
__global__ __launch_bounds__(256) void scores_gemm(
    const h1* __restrict__ Qh, const h1* __restrict__ Kh,
    h1* __restrict__ Eh,             // [NB][SL][SL] shifted unnormalized exp, fp16
    float* __restrict__ partial)     // [MM][64] per-(row, ntile*2+wn) partial sums
{
    const int b  = blockIdx.z;
    const int m0 = blockIdx.y * 128;
    const int n0 = blockIdx.x * 128;
    const h1* __restrict__ Qb = Qh + (size_t)b * SL * DD;
    const h1* __restrict__ Kb = Kh + (size_t)b * SL * DD;

    __shared__ h1 As[128*64];
    __shared__ h1 Bs[128*64];

    const int tid  = threadIdx.x;
    const int lane = tid & 63;
    const int wid  = tid >> 6;
    const int wm = wid >> 1, wn = wid & 1;
    const int g  = lane >> 4, c = lane & 15;

    f32x4 acc[4][4];
    #pragma unroll
    for (int i = 0; i < 4; i++)
        #pragma unroll
        for (int j = 0; j < 4; j++) acc[i][j] = (f32x4){0.f, 0.f, 0.f, 0.f};

    for (int k0 = 0; k0 < DD; k0 += 64) {
        __syncthreads();
        stage_tile(Qb + (size_t)m0 * DD + k0, As, wid, lane);
        stage_tile(Kb + (size_t)n0 * DD + k0, Bs, wid, lane);
        __syncthreads();
        #pragma unroll
        for (int kk = 0; kk < 2; kk++) {
            h8 af[4], bf[4];
            #pragma unroll
            for (int mf = 0; mf < 4; mf++) af[mf] = lds_frag(As, wm*64 + mf*16 + c, kk*4 + g);
            #pragma unroll
            for (int nf = 0; nf < 4; nf++) bf[nf] = lds_frag(Bs, wn*64 + nf*16 + c, kk*4 + g);
            #pragma unroll
            for (int mf = 0; mf < 4; mf++)
                #pragma unroll
                for (int nf = 0; nf < 4; nf++)
                    acc[mf][nf] = __builtin_amdgcn_mfma_f32_16x16x32_f16(af[mf], bf[nf], acc[mf][nf], 0, 0, 0);
        }
    }

    const float inv_scale = 0.08838834764831845f;   // 1/sqrt(128)
    #pragma unroll
    for (int mf = 0; mf < 4; mf++) {
        #pragma unroll
        for (int i = 0; i < 4; i++) {
            const int row = m0 + wm*64 + mf*16 + g*4 + i;
            h1* erow = Eh + ((size_t)b * SL + row) * SL;
            float rsum = 0.f;
            #pragma unroll
            for (int nf = 0; nf < 4; nf++) {
                const int col = n0 + wn*64 + nf*16 + c;
                float e = __expf(fmaf(acc[mf][nf][i], inv_scale, -SHIFT));
                erow[col] = (h1)e;
                rsum += e;
            }
            #pragma unroll
            for (int off = 1; off < 16; off <<= 1) rsum += __shfl_xor(rsum, off);
            if (c == 0)
                partial[((size_t)b * SL + row) * 64 + blockIdx.x * 2 + wn] = rsum;
        }
    }
}

// ---------------- K2b: rowsum -> reciprocal ----------------
__global__ __launch_bounds__(256) void rowsum_inv(
    const float* __restrict__ partial, float* __restrict__ invrow)
{
    int row = blockIdx.x * 256 + threadIdx.x;   // 0..MM-1
    const f4* p = (const f4*)(partial + (size_t)row * 64);
    float s = 0.f;
    #pragma unroll
    for (int i = 0; i < 16; i++) { f4 v = p[i]; s += v[0] + v[1] + v[2] + v[3]; }
    invrow[row] = 1.0f / s;
}

// ---------------- K3: weights = fp16 e * invrow -> f32 out (nontemporal stores) ----------------
__global__ __launch_bounds__(256) void normalize_k(
    const h1* __restrict__ Eh, const float* __restrict__ invrow,
    float* __restrict__ Wout)
{
    const size_t total8 = (size_t)NB * SL * SL / 8;     // h8 count
    size_t i = (size_t)blockIdx.x * blockDim.x + threadIdx.x;
    const size_t stride = (size_t)gridDim.x * blockDim.x;
    for (; i < total8; i += stride) {
        const int row = (int)(i >> 9);                  // 512 h8 per 4096-col row
        h8 v = ((const h8*)Eh)[i];
        const float s = invrow[row];
        f4 o0, o1;
        #pragma unroll
        for (int j = 0; j < 4; j++) { o0[j] = (float)v[j] * s; o1[j] = (float)v[4+j] * s; }
        __builtin_nontemporal_store(o0, ((f4*)Wout) + i*2);
        __builtin_nontemporal_store(o1, ((f4*)Wout) + i*2 + 1);
    }
}

extern "C" void kernel_launch(void* const* d_in, const int* in_sizes, int n_in,
                              void* d_out, int out_size, void* d_ws, size_t ws_size,
                              hipStream_t stream)
{
    const float* q  = (const float*)d_in[0];
    const float* k  = (const float*)d_in[1];
    const float* v  = (const float*)d_in[2];
    const float* Wq = (const float*)d_in[3];
    const float* bq = (const float*)d_in[4];
    const float* Wk = (const float*)d_in[5];
    const float* bk = (const float*)d_in[6];
    const float* Wv = (const float*)d_in[7];
    const float* bv = (const float*)d_in[8];

    float* out  = (float*)d_out;
    float* Vout = out;                                 // [NB,SL,DD] f32 (output 0 == V)
    float* Wout = out + (size_t)MM * DD;               // [NB,SL,SL] weights

    char* ws = (char*)d_ws;
    h1* Wh = (h1*)ws;                                              // 1.5 MB
    h1* Qh = (h1*)(ws + (size_t)3*DD*DD*2);                        // 16 MB
    h1* Kh = (h1*)((char*)Qh + (size_t)MM*DD*2);                   // 16 MB
    float* partial = (float*)((char*)Kh + (size_t)MM*DD*2);        // 4 MB
    float* invrow  = (float*)((char*)partial + (size_t)MM*64*4);   // 64 KB
    h1* Eh = (h1*)((char*)invrow + (size_t)MM*4);                  // 134 MB

    convert_w_kernel<<<768, 256, 0, stream>>>(Wq, Wk, Wv, Wh);
    proj_gemm<<<dim3(4, 128, 3), 256, 0, stream>>>(q, k, v, Wh, bq, bk, bv, Qh, Kh, Vout);
    scores_gemm<<<dim3(32, 32, NB), 256, 0, stream>>>(Qh, Kh, Eh, partial);
    rowsum_inv<<<MM / 256, 256, 0, stream>>>(partial, invrow);
    normalize_k<<<4096, 256, 0, stream>>>(Eh, invrow, Wout);
}

// Round 5
// 296.241 us; speedup vs baseline: 1.0494x; 1.0494x over previous
//
#include <hip/hip_runtime.h>
#include <cstdint>

typedef _Float16 h1;
typedef _Float16 h4 __attribute__((ext_vector_type(4)));
typedef _Float16 h8 __attribute__((ext_vector_type(8)));
typedef float    f4 __attribute__((ext_vector_type(4)));
typedef float    f32x4 __attribute__((ext_vector_type(4)));

#define NB 4
#define SL 4096
#define DD 512
#define MM (NB*SL)   // 16384 total rows
#define SHIFT 12.0f

// ---------------- K0: convert X(q,k,v) and W(q,k,v) f32 -> fp16 ----------------
__global__ __launch_bounds__(256) void convert_all(
    const float* __restrict__ Xq, const float* __restrict__ Xk, const float* __restrict__ Xv,
    const float* __restrict__ Wq, const float* __restrict__ Wk, const float* __restrict__ Wv,
    h1* __restrict__ Xh, h1* __restrict__ Wh)
{
    const int xper = MM*DD/4;             // f4 chunks per X matrix
    const int wper = DD*DD/4;
    const int xtot = 3*xper;
    int i = blockIdx.x * 256 + threadIdx.x;
    const float* src;
    h1* dst;
    int j;
    if (i < xtot) {
        int mat = i / xper; j = i - mat*xper;
        src = (mat==0) ? Xq : (mat==1 ? Xk : Xv);
        dst = Xh + (size_t)mat*MM*DD;
    } else {
        int t = i - xtot;
        if (t >= 3*wper) return;
        int mat = t / wper; j = t - mat*wper;
        src = (mat==0) ? Wq : (mat==1 ? Wk : Wv);
        dst = Wh + (size_t)mat*DD*DD;
    }
    f4 v = ((const f4*)src)[j];
    h4 hv;
    hv[0]=(h1)v[0]; hv[1]=(h1)v[1]; hv[2]=(h1)v[2]; hv[3]=(h1)v[3];
    ((h4*)dst)[j] = hv;
}

// ---------------- swizzled gload_lds staging (linear LDS dest, pre-swizzled src) ----------------
// LDS tile: 128 rows x 64 halves (16 KB) linear; (row, chunk s) holds global
// chunk s ^ (row&7), chunk = 16 B = 8 halves.
__device__ __forceinline__ void stage_tile(const h1* __restrict__ gbase,  // ptr at (tile_row0, k0)
                                           h1* lds, int w, int l)
{
    #pragma unroll
    for (int j = 0; j < 4; j++) {
        const int cc  = w*4 + j;                 // 1-KB chunk index (wave-uniform)
        const int row = cc*8 + (l >> 3);
        const int sc  = (l & 7) ^ (l >> 3);      // inverse-swizzled source chunk
        const h1* src = gbase + (size_t)row * DD + sc*8;
        void* dst = (char*)lds + cc*1024;
        __builtin_amdgcn_global_load_lds(
            (const __attribute__((address_space(1))) uint32_t*)src,
            (__attribute__((address_space(3))) uint32_t*)dst, 16, 0, 0);
    }
}

__device__ __forceinline__ h8 lds_frag(const h1* lds, int row, int lc)
{
    const int chunk = lc ^ (row & 7);
    return *(const h8*)(lds + row*64 + chunk*8);
}

// ---------------- K1: X @ W^T + b for Q,K,V (pure fp16 NT GEMM) ----------------
__global__ __launch_bounds__(256) void proj_gemm(
    const h1* __restrict__ Xh, const h1* __restrict__ Wh,
    const float* __restrict__ bq, const float* __restrict__ bk, const float* __restrict__ bv,
    h1* __restrict__ Qh, h1* __restrict__ Kh, float* __restrict__ Vout)
{
    const int prj = blockIdx.z;
    const h1* __restrict__ X    = Xh + (size_t)prj * MM * DD;
    const h1* __restrict__ W    = Wh + (size_t)prj * DD * DD;
    const float* __restrict__ bias = (prj==0) ? bq : (prj==1 ? bk : bv);

    const int m0 = blockIdx.y * 128;
    const int n0 = blockIdx.x * 128;

    __shared__ h1 As[128*64];
    __shared__ h1 Bs[128*64];

    const int tid  = threadIdx.x;
    const int lane = tid & 63;
    const int wid  = tid >> 6;
    const int wm = wid >> 1, wn = wid & 1;      // 2x2 wave grid, each 64x64
    const int g  = lane >> 4, c = lane & 15;

    f32x4 acc[4][4];
    #pragma unroll
    for (int i = 0; i < 4; i++)
        #pragma unroll
        for (int j = 0; j < 4; j++) acc[i][j] = (f32x4){0.f, 0.f, 0.f, 0.f};

    for (int k0 = 0; k0 < DD; k0 += 64) {
        __syncthreads();
        stage_tile(X + (size_t)m0 * DD + k0, As, wid, lane);
        stage_tile(W + (size_t)n0 * DD + k0, Bs, wid, lane);
        __syncthreads();
        #pragma unroll
        for (int kk = 0; kk < 2; kk++) {
            h8 af[4], bf[4];
            #pragma unroll
            for (int mf = 0; mf < 4; mf++) af[mf] = lds_frag(As, wm*64 + mf*16 + c, kk*4 + g);
            #pragma unroll
            for (int nf = 0; nf < 4; nf++) bf[nf] = lds_frag(Bs, wn*64 + nf*16 + c, kk*4 + g);
            #pragma unroll
            for (int mf = 0; mf < 4; mf++)
                #pragma unroll
                for (int nf = 0; nf < 4; nf++)
                    acc[mf][nf] = __builtin_amdgcn_mfma_f32_16x16x32_f16(af[mf], bf[nf], acc[mf][nf], 0, 0, 0);
        }
    }

    float bv4[4];
    #pragma unroll
    for (int nf = 0; nf < 4; nf++) bv4[nf] = bias[n0 + wn*64 + nf*16 + c];

    #pragma unroll
    for (int mf = 0; mf < 4; mf++) {
        #pragma unroll
        for (int i = 0; i < 4; i++) {
            const int row = m0 + wm*64 + mf*16 + g*4 + i;
            #pragma unroll
            for (int nf = 0; nf < 4; nf++) {
                const int col = n0 + wn*64 + nf*16 + c;
                float vv = acc[mf][nf][i] + bv4[nf];
                if (prj == 0)      Qh[(size_t)row*DD + col] = (h1)vv;
                else if (prj == 1) Kh[(size_t)row*DD + col] = (h1)vv;
                else               Vout[(size_t)row*DD + col] = vv;
            }
        }
    }
}

// ---------------- K2: e = exp(QK^T/sqrt(128) - 12) fp16; row partial sums ----------------
// 1-D grid of 4096 blocks with bijective XCD-chunk swizzle (T1): each XCD gets
// 512 contiguous y-major tiles -> K-panel re-reads are L2-local.
__global__ __launch_bounds__(256) void scores_gemm(
    const h1* __restrict__ Qh, const h1* __restrict__ Kh,
    h1* __restrict__ Eh,             // [NB][SL][SL] shifted unnormalized exp, fp16
    float* __restrict__ partial)     // [MM][64] per-(row, ntile*2+wn) partial sums
{
    // swizzle: orig -> xcd*512 + orig/8  (4096 % 8 == 0, bijective)
    const int orig = blockIdx.x;
    const int swz  = (orig & 7) * 512 + (orig >> 3);
    const int b  = swz >> 10;            // 1024 tiles per batch
    const int t  = swz & 1023;
    const int ty = t >> 5;               // 32 n-tiles per row-panel
    const int tx = t & 31;
    const int m0 = ty * 128;
    const int n0 = tx * 128;
    const h1* __restrict__ Qb = Qh + (size_t)b * SL * DD;
    const h1* __restrict__ Kb = Kh + (size_t)b * SL * DD;

    __shared__ h1 As[128*64];
    __shared__ h1 Bs[128*64];

    const int tid  = threadIdx.x;
    const int lane = tid & 63;
    const int wid  = tid >> 6;
    const int wm = wid >> 1, wn = wid & 1;
    const int g  = lane >> 4, c = lane & 15;

    f32x4 acc[4][4];
    #pragma unroll
    for (int i = 0; i < 4; i++)
        #pragma unroll
        for (int j = 0; j < 4; j++) acc[i][j] = (f32x4){0.f, 0.f, 0.f, 0.f};

    for (int k0 = 0; k0 < DD; k0 += 64) {
        __syncthreads();
        stage_tile(Qb + (size_t)m0 * DD + k0, As, wid, lane);
        stage_tile(Kb + (size_t)n0 * DD + k0, Bs, wid, lane);
        __syncthreads();
        #pragma unroll
        for (int kk = 0; kk < 2; kk++) {
            h8 af[4], bf[4];
            #pragma unroll
            for (int mf = 0; mf < 4; mf++) af[mf] = lds_frag(As, wm*64 + mf*16 + c, kk*4 + g);
            #pragma unroll
            for (int nf = 0; nf < 4; nf++) bf[nf] = lds_frag(Bs, wn*64 + nf*16 + c, kk*4 + g);
            #pragma unroll
            for (int mf = 0; mf < 4; mf++)
                #pragma unroll
                for (int nf = 0; nf < 4; nf++)
                    acc[mf][nf] = __builtin_amdgcn_mfma_f32_16x16x32_f16(af[mf], bf[nf], acc[mf][nf], 0, 0, 0);
        }
    }

    const float inv_scale = 0.08838834764831845f;   // 1/sqrt(128)
    #pragma unroll
    for (int mf = 0; mf < 4; mf++) {
        #pragma unroll
        for (int i = 0; i < 4; i++) {
            const int row = m0 + wm*64 + mf*16 + g*4 + i;
            h1* erow = Eh + ((size_t)b * SL + row) * SL;
            float rsum = 0.f;
            #pragma unroll
            for (int nf = 0; nf < 4; nf++) {
                const int col = n0 + wn*64 + nf*16 + c;
                float e = __expf(fmaf(acc[mf][nf][i], inv_scale, -SHIFT));
                erow[col] = (h1)e;
                rsum += e;
            }
            #pragma unroll
            for (int off = 1; off < 16; off <<= 1) rsum += __shfl_xor(rsum, off);
            if (c == 0)
                partial[((size_t)b * SL + row) * 64 + tx * 2 + wn] = rsum;
        }
    }
}

// ---------------- K2b: rowsum -> reciprocal ----------------
__global__ __launch_bounds__(256) void rowsum_inv(
    const float* __restrict__ partial, float* __restrict__ invrow)
{
    int row = blockIdx.x * 256 + threadIdx.x;   // 0..MM-1
    const f4* p = (const f4*)(partial + (size_t)row * 64);
    float s = 0.f;
    #pragma unroll
    for (int i = 0; i < 16; i++) { f4 v = p[i]; s += v[0] + v[1] + v[2] + v[3]; }
    invrow[row] = 1.0f / s;
}

// ---------------- K3: weights = fp16 e * invrow -> f32 out ----------------
__global__ __launch_bounds__(256) void normalize_k(
    const h1* __restrict__ Eh, const float* __restrict__ invrow,
    float* __restrict__ Wout)
{
    const size_t total8 = (size_t)NB * SL * SL / 8;     // h8 count
    size_t i = (size_t)blockIdx.x * blockDim.x + threadIdx.x;
    const size_t stride = (size_t)gridDim.x * blockDim.x;
    for (; i < total8; i += stride) {
        const int row = (int)(i >> 9);                  // 512 h8 per 4096-col row
        h8 v = ((const h8*)Eh)[i];
        const float s = invrow[row];
        f4 o0, o1;
        #pragma unroll
        for (int j = 0; j < 4; j++) { o0[j] = (float)v[j] * s; o1[j] = (float)v[4+j] * s; }
        ((f4*)Wout)[i*2]   = o0;
        ((f4*)Wout)[i*2+1] = o1;
    }
}

extern "C" void kernel_launch(void* const* d_in, const int* in_sizes, int n_in,
                              void* d_out, int out_size, void* d_ws, size_t ws_size,
                              hipStream_t stream)
{
    const float* q  = (const float*)d_in[0];
    const float* k  = (const float*)d_in[1];
    const float* v  = (const float*)d_in[2];
    const float* Wq = (const float*)d_in[3];
    const float* bq = (const float*)d_in[4];
    const float* Wk = (const float*)d_in[5];
    const float* bk = (const float*)d_in[6];
    const float* Wv = (const float*)d_in[7];
    const float* bv = (const float*)d_in[8];

    float* out  = (float*)d_out;
    float* Vout = out;                                 // [NB,SL,DD] f32 (output 0 == V)
    float* Wout = out + (size_t)MM * DD;               // [NB,SL,SL] weights

    char* ws = (char*)d_ws;
    h1* Xh = (h1*)ws;                                              // 48 MB
    h1* Wh = (h1*)(ws + (size_t)3*MM*DD*2);                        // 1.5 MB
    h1* Qh = (h1*)((char*)Wh + (size_t)3*DD*DD*2);                 // 16 MB
    h1* Kh = (h1*)((char*)Qh + (size_t)MM*DD*2);                   // 16 MB
    float* partial = (float*)((char*)Kh + (size_t)MM*DD*2);        // 4 MB
    float* invrow  = (float*)((char*)partial + (size_t)MM*64*4);   // 64 KB
    h1* Eh = (h1*)((char*)invrow + (size_t)MM*4);                  // 134 MB

    const int conv_chunks = (3*MM*DD + 3*DD*DD) / 4;
    convert_all<<<(conv_chunks + 255)/256, 256, 0, stream>>>(q, k, v, Wq, Wk, Wv, Xh, Wh);
    proj_gemm<<<dim3(4, 128, 3), 256, 0, stream>>>(Xh, Wh, bq, bk, bv, Qh, Kh, Vout);
    scores_gemm<<<4096, 256, 0, stream>>>(Qh, Kh, Eh, partial);
    rowsum_inv<<<MM / 256, 256, 0, stream>>>(partial, invrow);
    normalize_k<<<2048, 256, 0, stream>>>(Eh, invrow, Wout);
}

// Round 7
// 286.456 us; speedup vs baseline: 1.0853x; 1.0342x over previous
//
#include <hip/hip_runtime.h>
#include <cstdint>

typedef _Float16 h1;
typedef _Float16 h4 __attribute__((ext_vector_type(4)));
typedef _Float16 h8 __attribute__((ext_vector_type(8)));
typedef float    f4 __attribute__((ext_vector_type(4)));
typedef float    f32x4 __attribute__((ext_vector_type(4)));

#define NB 4
#define SL 4096
#define DD 512
#define MM (NB*SL)   // 16384 total rows
#define SHIFT 12.0f

// ---------------- K0: convert X(q,k,v) and W(q,k,v) f32 -> fp16 ----------------
__global__ __launch_bounds__(256) void convert_all(
    const float* __restrict__ Xq, const float* __restrict__ Xk, const float* __restrict__ Xv,
    const float* __restrict__ Wq, const float* __restrict__ Wk, const float* __restrict__ Wv,
    h1* __restrict__ Xh, h1* __restrict__ Wh)
{
    const int xper = MM*DD/4;             // f4 chunks per X matrix
    const int wper = DD*DD/4;
    const int xtot = 3*xper;
    int i = blockIdx.x * 256 + threadIdx.x;
    const float* src;
    h1* dst;
    int j;
    if (i < xtot) {
        int mat = i / xper; j = i - mat*xper;
        src = (mat==0) ? Xq : (mat==1 ? Xk : Xv);
        dst = Xh + (size_t)mat*MM*DD;
    } else {
        int t = i - xtot;
        if (t >= 3*wper) return;
        int mat = t / wper; j = t - mat*wper;
        src = (mat==0) ? Wq : (mat==1 ? Wk : Wv);
        dst = Wh + (size_t)mat*DD*DD;
    }
    f4 v = ((const f4*)src)[j];
    h4 hv;
    hv[0]=(h1)v[0]; hv[1]=(h1)v[1]; hv[2]=(h1)v[2]; hv[3]=(h1)v[3];
    ((h4*)dst)[j] = hv;
}

// ---------------- swizzled gload_lds staging (linear LDS dest, pre-swizzled src) ----------------
// LDS rows of 64 halves; (row, slot s) holds global chunk s ^ (row&7), chunk = 16 B.
__device__ __forceinline__ void stage_tile(const h1* __restrict__ gbase,
                                           h1* lds, int w, int l)
{
    #pragma unroll
    for (int j = 0; j < 4; j++) {
        const int cc  = w*4 + j;
        const int row = cc*8 + (l >> 3);
        const int sc  = (l & 7) ^ (l >> 3);
        const h1* src = gbase + (size_t)row * DD + sc*8;
        void* dst = (char*)lds + cc*1024;
        __builtin_amdgcn_global_load_lds(
            (const __attribute__((address_space(1))) uint32_t*)src,
            (__attribute__((address_space(3))) uint32_t*)dst, 16, 0, 0);
    }
}

// 128-row (16 KB) half-tile stage for the 512-thread kernel: 8 waves x 2 chunks
__device__ __forceinline__ void stage_half(const h1* __restrict__ gbase,
                                           char* ldsbase, int w, int l)
{
    #pragma unroll
    for (int j = 0; j < 2; j++) {
        const int cc  = w*2 + j;                 // 0..15
        const int row = cc*8 + (l >> 3);         // 0..127
        const int sc  = (l & 7) ^ (l >> 3);
        const h1* src = gbase + (size_t)row * DD + sc*8;
        __builtin_amdgcn_global_load_lds(
            (const __attribute__((address_space(1))) uint32_t*)src,
            (__attribute__((address_space(3))) uint32_t*)(ldsbase + cc*1024), 16, 0, 0);
    }
}

__device__ __forceinline__ h8 lds_frag(const h1* lds, int row, int lc)
{
    const int chunk = lc ^ (row & 7);
    return *(const h8*)(lds + row*64 + chunk*8);
}

// ---------------- K1: X @ W^T + b for Q,K,V (pure fp16 NT GEMM) ----------------
__global__ __launch_bounds__(256) void proj_gemm(
    const h1* __restrict__ Xh, const h1* __restrict__ Wh,
    const float* __restrict__ bq, const float* __restrict__ bk, const float* __restrict__ bv,
    h1* __restrict__ Qh, h1* __restrict__ Kh, float* __restrict__ Vout)
{
    const int prj = blockIdx.z;
    const h1* __restrict__ X    = Xh + (size_t)prj * MM * DD;
    const h1* __restrict__ W    = Wh + (size_t)prj * DD * DD;
    const float* __restrict__ bias = (prj==0) ? bq : (prj==1 ? bk : bv);

    const int m0 = blockIdx.y * 128;
    const int n0 = blockIdx.x * 128;

    __shared__ h1 As[128*64];
    __shared__ h1 Bs[128*64];

    const int tid  = threadIdx.x;
    const int lane = tid & 63;
    const int wid  = tid >> 6;
    const int wm = wid >> 1, wn = wid & 1;
    const int g  = lane >> 4, c = lane & 15;

    f32x4 acc[4][4];
    #pragma unroll
    for (int i = 0; i < 4; i++)
        #pragma unroll
        for (int j = 0; j < 4; j++) acc[i][j] = (f32x4){0.f, 0.f, 0.f, 0.f};

    for (int k0 = 0; k0 < DD; k0 += 64) {
        __syncthreads();
        stage_tile(X + (size_t)m0 * DD + k0, As, wid, lane);
        stage_tile(W + (size_t)n0 * DD + k0, Bs, wid, lane);
        __syncthreads();
        #pragma unroll
        for (int kk = 0; kk < 2; kk++) {
            h8 af[4], bf[4];
            #pragma unroll
            for (int mf = 0; mf < 4; mf++) af[mf] = lds_frag(As, wm*64 + mf*16 + c, kk*4 + g);
            #pragma unroll
            for (int nf = 0; nf < 4; nf++) bf[nf] = lds_frag(Bs, wn*64 + nf*16 + c, kk*4 + g);
            #pragma unroll
            for (int mf = 0; mf < 4; mf++)
                #pragma unroll
                for (int nf = 0; nf < 4; nf++)
                    acc[mf][nf] = __builtin_amdgcn_mfma_f32_16x16x32_f16(af[mf], bf[nf], acc[mf][nf], 0, 0, 0);
        }
    }

    float bv4[4];
    #pragma unroll
    for (int nf = 0; nf < 4; nf++) bv4[nf] = bias[n0 + wn*64 + nf*16 + c];

    #pragma unroll
    for (int mf = 0; mf < 4; mf++) {
        #pragma unroll
        for (int i = 0; i < 4; i++) {
            const int row = m0 + wm*64 + mf*16 + g*4 + i;
            #pragma unroll
            for (int nf = 0; nf < 4; nf++) {
                const int col = n0 + wn*64 + nf*16 + c;
                float vv = acc[mf][nf][i] + bv4[nf];
                if (prj == 0)      Qh[(size_t)row*DD + col] = (h1)vv;
                else if (prj == 1) Kh[(size_t)row*DD + col] = (h1)vv;
                else               Vout[(size_t)row*DD + col] = vv;
            }
        }
    }
}

// ---------------- K2: 256x256 8-phase-style scores GEMM; e = exp(s/sqrt(128)-12) fp16 ----------------
// 512 threads = 8 waves (2M x 4N). BK=64, 8 K-steps, 2-slot double buffer (128 KB LDS).
// Per K-step: 4 phases x {12 ds_read || (phase 0: prefetch next K-tile) -> barrier ->
// lgkmcnt(0) -> setprio(1) 16 MFMA setprio(0) -> [phase 3: vmcnt(0)] -> barrier}.
__global__ __launch_bounds__(512) void scores_gemm_8ph(
    const h1* __restrict__ Qh, const h1* __restrict__ Kh,
    h1* __restrict__ Eh,
    float* __restrict__ partial)     // [MM][64]: slot = tx*4 + wn
{
    // T1 bijective XCD swizzle over 1024 blocks
    const int orig = blockIdx.x;
    const int swz  = (orig & 7) * 128 + (orig >> 3);
    const int b  = swz >> 8;             // 256 tiles per batch
    const int t_ = swz & 255;
    const int ty = t_ >> 4;
    const int tx = t_ & 15;
    const int m0 = ty * 256;
    const int n0 = tx * 256;
    const h1* __restrict__ Qb = Qh + (size_t)b * SL * DD;
    const h1* __restrict__ Kb = Kh + (size_t)b * SL * DD;

    // 2 slots per operand; slot = 256 rows x 64 halves = 32 KB. Total 128 KB.
    __shared__ h1 Albuf[2*256*64];
    __shared__ h1 Blbuf[2*256*64];
    const int SLOT_H = 256*64;           // halves per slot
    const int SLOT_B = SLOT_H*2;         // bytes per slot

    const int tid  = threadIdx.x;
    const int lane = tid & 63;
    const int wid  = tid >> 6;           // 0..7
    const int wm = wid >> 2;             // 0..1 (row half: 128 rows)
    const int wn = wid & 3;              // 0..3 (col quarter: 64 cols)
    const int g  = lane >> 4, c = lane & 15;

    f32x4 acc[8][4];
    #pragma unroll
    for (int i = 0; i < 8; i++)
        #pragma unroll
        for (int j = 0; j < 4; j++) acc[i][j] = (f32x4){0.f, 0.f, 0.f, 0.f};

    // prologue: stage K-tile 0 into slot 0
    stage_half(Qb + (size_t)m0*DD,            (char*)Albuf,          wid, lane);
    stage_half(Qb + (size_t)(m0+128)*DD,      (char*)Albuf + 16384,  wid, lane);
    stage_half(Kb + (size_t)n0*DD,            (char*)Blbuf,          wid, lane);
    stage_half(Kb + (size_t)(n0+128)*DD,      (char*)Blbuf + 16384,  wid, lane);
    asm volatile("s_waitcnt vmcnt(0)" ::: "memory");
    __builtin_amdgcn_s_barrier();

    for (int kt = 0; kt < 8; ++kt) {
        const int cur = kt & 1;
        const h1* Abase = Albuf + cur*SLOT_H;
        const h1* Bbase = Blbuf + cur*SLOT_H;
        #pragma unroll
        for (int q = 0; q < 4; q++) {
            const int mh = q >> 1, nh = q & 1;

            // ds-load register subtile (12 x ds_read_b128)
            h8 af[4][2], bf[2][2];
            #pragma unroll
            for (int fm = 0; fm < 4; fm++)
                #pragma unroll
                for (int ks = 0; ks < 2; ks++)
                    af[fm][ks] = lds_frag(Abase, wm*128 + (mh*4+fm)*16 + c, ks*4 + g);
            #pragma unroll
            for (int fn = 0; fn < 2; fn++)
                #pragma unroll
                for (int ks = 0; ks < 2; ks++)
                    bf[fn][ks] = lds_frag(Bbase, wn*64 + (nh*2+fn)*16 + c, ks*4 + g);

            // phase 0: prefetch next K-tile into the opposite slot
            if (q == 0 && kt < 7) {
                const int k0n = (kt+1) * 64;
                char* Adst = (char*)Albuf + (cur^1)*SLOT_B;
                char* Bdst = (char*)Blbuf + (cur^1)*SLOT_B;
                stage_half(Qb + (size_t)m0*DD + k0n,       Adst,         wid, lane);
                stage_half(Qb + (size_t)(m0+128)*DD + k0n, Adst + 16384, wid, lane);
                stage_half(Kb + (size_t)n0*DD + k0n,       Bdst,         wid, lane);
                stage_half(Kb + (size_t)(n0+128)*DD + k0n, Bdst + 16384, wid, lane);
            }

            __builtin_amdgcn_s_barrier();
            asm volatile("s_waitcnt lgkmcnt(0)" ::: "memory");
            __builtin_amdgcn_sched_barrier(0);
            __builtin_amdgcn_s_setprio(1);
            #pragma unroll
            for (int fm = 0; fm < 4; fm++)
                #pragma unroll
                for (int fn = 0; fn < 2; fn++)
                    #pragma unroll
                    for (int ks = 0; ks < 2; ks++)
                        acc[mh*4+fm][nh*2+fn] = __builtin_amdgcn_mfma_f32_16x16x32_f16(
                            af[fm][ks], bf[fn][ks], acc[mh*4+fm][nh*2+fn], 0, 0, 0);
            __builtin_amdgcn_s_setprio(0);
            if (q == 3) asm volatile("s_waitcnt vmcnt(0)" ::: "memory");
            __builtin_amdgcn_s_barrier();
        }
    }

    // epilogue: exp + fp16 store + per-row partial sums
    const float inv_scale = 0.08838834764831845f;   // 1/sqrt(128)
    #pragma unroll
    for (int mf = 0; mf < 8; mf++) {
        #pragma unroll
        for (int i = 0; i < 4; i++) {
            const int row = m0 + wm*128 + mf*16 + g*4 + i;
            h1* erow = Eh + ((size_t)b * SL + row) * SL;
            float rsum = 0.f;
            #pragma unroll
            for (int nf = 0; nf < 4; nf++) {
                const int col = n0 + wn*64 + nf*16 + c;
                float e = __expf(fmaf(acc[mf][nf][i], inv_scale, -SHIFT));
                erow[col] = (h1)e;
                rsum += e;
            }
            #pragma unroll
            for (int off = 1; off < 16; off <<= 1) rsum += __shfl_xor(rsum, off);
            if (c == 0)
                partial[((size_t)b * SL + row) * 64 + tx * 4 + wn] = rsum;
        }
    }
}

// ---------------- K2b: rowsum -> reciprocal ----------------
__global__ __launch_bounds__(256) void rowsum_inv(
    const float* __restrict__ partial, float* __restrict__ invrow)
{
    int row = blockIdx.x * 256 + threadIdx.x;   // 0..MM-1
    const f4* p = (const f4*)(partial + (size_t)row * 64);
    float s = 0.f;
    #pragma unroll
    for (int i = 0; i < 16; i++) { f4 v = p[i]; s += v[0] + v[1] + v[2] + v[3]; }
    invrow[row] = 1.0f / s;
}

// ---------------- K3: weights = fp16 e * invrow -> f32 out ----------------
__global__ __launch_bounds__(256) void normalize_k(
    const h1* __restrict__ Eh, const float* __restrict__ invrow,
    float* __restrict__ Wout)
{
    const size_t total8 = (size_t)NB * SL * SL / 8;     // h8 count
    size_t i = (size_t)blockIdx.x * blockDim.x + threadIdx.x;
    const size_t stride = (size_t)gridDim.x * blockDim.x;
    for (; i < total8; i += stride) {
        const int row = (int)(i >> 9);                  // 512 h8 per 4096-col row
        h8 v = ((const h8*)Eh)[i];
        const float s = invrow[row];
        f4 o0, o1;
        #pragma unroll
        for (int j = 0; j < 4; j++) { o0[j] = (float)v[j] * s; o1[j] = (float)v[4+j] * s; }
        ((f4*)Wout)[i*2]   = o0;
        ((f4*)Wout)[i*2+1] = o1;
    }
}

extern "C" void kernel_launch(void* const* d_in, const int* in_sizes, int n_in,
                              void* d_out, int out_size, void* d_ws, size_t ws_size,
                              hipStream_t stream)
{
    const float* q  = (const float*)d_in[0];
    const float* k  = (const float*)d_in[1];
    const float* v  = (const float*)d_in[2];
    const float* Wq = (const float*)d_in[3];
    const float* bq = (const float*)d_in[4];
    const float* Wk = (const float*)d_in[5];
    const float* bk = (const float*)d_in[6];
    const float* Wv = (const float*)d_in[7];
    const float* bv = (const float*)d_in[8];

    float* out  = (float*)d_out;
    float* Vout = out;                                 // [NB,SL,DD] f32 (output 0 == V)
    float* Wout = out + (size_t)MM * DD;               // [NB,SL,SL] weights

    char* ws = (char*)d_ws;
    h1* Xh = (h1*)ws;                                              // 48 MB
    h1* Wh = (h1*)(ws + (size_t)3*MM*DD*2);                        // 1.5 MB
    h1* Qh = (h1*)((char*)Wh + (size_t)3*DD*DD*2);                 // 16 MB
    h1* Kh = (h1*)((char*)Qh + (size_t)MM*DD*2);                   // 16 MB
    float* partial = (float*)((char*)Kh + (size_t)MM*DD*2);        // 4 MB
    float* invrow  = (float*)((char*)partial + (size_t)MM*64*4);   // 64 KB
    h1* Eh = (h1*)((char*)invrow + (size_t)MM*4);                  // 134 MB

    const int conv_chunks = (3*MM*DD + 3*DD*DD) / 4;
    convert_all<<<(conv_chunks + 255)/256, 256, 0, stream>>>(q, k, v, Wq, Wk, Wv, Xh, Wh);
    proj_gemm<<<dim3(4, 128, 3), 256, 0, stream>>>(Xh, Wh, bq, bk, bv, Qh, Kh, Vout);
    scores_gemm_8ph<<<1024, 512, 0, stream>>>(Qh, Kh, Eh, partial);
    rowsum_inv<<<MM / 256, 256, 0, stream>>>(partial, invrow);
    normalize_k<<<2048, 256, 0, stream>>>(Eh, invrow, Wout);
}

// Round 8
// 285.320 us; speedup vs baseline: 1.0896x; 1.0040x over previous
//
#include <hip/hip_runtime.h>
#include <cstdint>

typedef _Float16 h1;
typedef _Float16 h4 __attribute__((ext_vector_type(4)));
typedef _Float16 h8 __attribute__((ext_vector_type(8)));
typedef float    f4 __attribute__((ext_vector_type(4)));
typedef float    f32x4 __attribute__((ext_vector_type(4)));

#define NB 4
#define SL 4096
#define DD 512
#define MM (NB*SL)   // 16384 total rows
#define SHIFT 12.0f

// ---------------- K0: convert X(q,k,v) and W(q,k,v) f32 -> fp16 ----------------
__global__ __launch_bounds__(256) void convert_all(
    const float* __restrict__ Xq, const float* __restrict__ Xk, const float* __restrict__ Xv,
    const float* __restrict__ Wq, const float* __restrict__ Wk, const float* __restrict__ Wv,
    h1* __restrict__ Xh, h1* __restrict__ Wh)
{
    const int xper = MM*DD/4;             // f4 chunks per X matrix
    const int wper = DD*DD/4;
    const int xtot = 3*xper;
    int i = blockIdx.x * 256 + threadIdx.x;
    const float* src;
    h1* dst;
    int j;
    if (i < xtot) {
        int mat = i / xper; j = i - mat*xper;
        src = (mat==0) ? Xq : (mat==1 ? Xk : Xv);
        dst = Xh + (size_t)mat*MM*DD;
    } else {
        int t = i - xtot;
        if (t >= 3*wper) return;
        int mat = t / wper; j = t - mat*wper;
        src = (mat==0) ? Wq : (mat==1 ? Wk : Wv);
        dst = Wh + (size_t)mat*DD*DD;
    }
    f4 v = ((const f4*)src)[j];
    h4 hv;
    hv[0]=(h1)v[0]; hv[1]=(h1)v[1]; hv[2]=(h1)v[2]; hv[3]=(h1)v[3];
    ((h4*)dst)[j] = hv;
}

// ---------------- K1 staging: 128x64 tile, XOR-8 chunk swizzle ----------------
__device__ __forceinline__ void stage_tile(const h1* __restrict__ gbase,
                                           h1* lds, int w, int l)
{
    #pragma unroll
    for (int j = 0; j < 4; j++) {
        const int cc  = w*4 + j;
        const int row = cc*8 + (l >> 3);
        const int sc  = (l & 7) ^ (l >> 3);
        const h1* src = gbase + (size_t)row * DD + sc*8;
        void* dst = (char*)lds + cc*1024;
        __builtin_amdgcn_global_load_lds(
            (const __attribute__((address_space(1))) uint32_t*)src,
            (__attribute__((address_space(3))) uint32_t*)dst, 16, 0, 0);
    }
}

__device__ __forceinline__ h8 lds_frag(const h1* lds, int row, int lc)
{
    const int chunk = lc ^ (row & 7);
    return *(const h8*)(lds + row*64 + chunk*8);
}

// ---------------- K1: X @ W^T + b for Q,K,V (pure fp16 NT GEMM) ----------------
__global__ __launch_bounds__(256) void proj_gemm(
    const h1* __restrict__ Xh, const h1* __restrict__ Wh,
    const float* __restrict__ bq, const float* __restrict__ bk, const float* __restrict__ bv,
    h1* __restrict__ Qh, h1* __restrict__ Kh, float* __restrict__ Vout)
{
    const int prj = blockIdx.z;
    const h1* __restrict__ X    = Xh + (size_t)prj * MM * DD;
    const h1* __restrict__ W    = Wh + (size_t)prj * DD * DD;
    const float* __restrict__ bias = (prj==0) ? bq : (prj==1 ? bk : bv);

    const int m0 = blockIdx.y * 128;
    const int n0 = blockIdx.x * 128;

    __shared__ h1 As[128*64];
    __shared__ h1 Bs[128*64];

    const int tid  = threadIdx.x;
    const int lane = tid & 63;
    const int wid  = tid >> 6;
    const int wm = wid >> 1, wn = wid & 1;
    const int g  = lane >> 4, c = lane & 15;

    f32x4 acc[4][4];
    #pragma unroll
    for (int i = 0; i < 4; i++)
        #pragma unroll
        for (int j = 0; j < 4; j++) acc[i][j] = (f32x4){0.f, 0.f, 0.f, 0.f};

    for (int k0 = 0; k0 < DD; k0 += 64) {
        __syncthreads();
        stage_tile(X + (size_t)m0 * DD + k0, As, wid, lane);
        stage_tile(W + (size_t)n0 * DD + k0, Bs, wid, lane);
        __syncthreads();
        #pragma unroll
        for (int kk = 0; kk < 2; kk++) {
            h8 af[4], bf[4];
            #pragma unroll
            for (int mf = 0; mf < 4; mf++) af[mf] = lds_frag(As, wm*64 + mf*16 + c, kk*4 + g);
            #pragma unroll
            for (int nf = 0; nf < 4; nf++) bf[nf] = lds_frag(Bs, wn*64 + nf*16 + c, kk*4 + g);
            #pragma unroll
            for (int mf = 0; mf < 4; mf++)
                #pragma unroll
                for (int nf = 0; nf < 4; nf++)
                    acc[mf][nf] = __builtin_amdgcn_mfma_f32_16x16x32_f16(af[mf], bf[nf], acc[mf][nf], 0, 0, 0);
        }
    }

    float bv4[4];
    #pragma unroll
    for (int nf = 0; nf < 4; nf++) bv4[nf] = bias[n0 + wn*64 + nf*16 + c];

    #pragma unroll
    for (int mf = 0; mf < 4; mf++) {
        #pragma unroll
        for (int i = 0; i < 4; i++) {
            const int row = m0 + wm*64 + mf*16 + g*4 + i;
            #pragma unroll
            for (int nf = 0; nf < 4; nf++) {
                const int col = n0 + wn*64 + nf*16 + c;
                float vv = acc[mf][nf][i] + bv4[nf];
                if (prj == 0)      Qh[(size_t)row*DD + col] = (h1)vv;
                else if (prj == 1) Kh[(size_t)row*DD + col] = (h1)vv;
                else               Vout[(size_t)row*DD + col] = vv;
            }
        }
    }
}

// ---------------- K2 staging: 256x32 slot (16 KB), chunk swizzle g^((row>>1)&3) ----------------
// Linear LDS [256][32]h; (row, phys ch) holds global chunk ch ^ ((row>>1)&3).
__device__ __forceinline__ void stage_slot32(const h1* __restrict__ gbase,
                                             char* ldsbase, int w, int l)
{
    #pragma unroll
    for (int j = 0; j < 2; j++) {
        const int lc  = j*512 + w*64 + l;    // linear 16B-chunk index 0..1023
        const int row = lc >> 2;
        const int ch  = lc & 3;
        const int sc  = ch ^ ((row >> 1) & 3);
        const h1* src = gbase + (size_t)row * DD + sc*8;
        // wave-uniform dest base; HW adds lane*16
        __builtin_amdgcn_global_load_lds(
            (const __attribute__((address_space(1))) uint32_t*)src,
            (__attribute__((address_space(3))) uint32_t*)(ldsbase + (size_t)(j*512 + w*64)*16),
            16, 0, 0);
    }
}

__device__ __forceinline__ h8 frag32(const h1* lds, int row, int g)
{
    const int ch = g ^ ((row >> 1) & 3);
    return *(const h8*)(lds + row*32 + ch*8);
}

// ---------------- K2: 256x256 counted-vmcnt pipelined scores GEMM ----------------
// 512 threads = 8 waves (2M x 4N). BK=32, 16 K-steps, 4-slot ring (128 KB LDS),
// depth-3 prefetch, steady-state wait = vmcnt(8) (4 loads/step x 2 steps in flight).
__global__ __launch_bounds__(512) void scores_gemm_8ph(
    const h1* __restrict__ Qh, const h1* __restrict__ Kh,
    h1* __restrict__ Eh,
    float* __restrict__ partial)     // [MM][64]: slot = tx*4 + wn
{
    // T1 bijective XCD swizzle over 1024 blocks
    const int orig = blockIdx.x;
    const int swz  = (orig & 7) * 128 + (orig >> 3);
    const int b  = swz >> 8;             // 256 tiles per batch
    const int t_ = swz & 255;
    const int ty = t_ >> 4;
    const int tx = t_ & 15;
    const int m0 = ty * 256;
    const int n0 = tx * 256;
    const h1* __restrict__ Qb = Qh + (size_t)b * SL * DD;
    const h1* __restrict__ Kb = Kh + (size_t)b * SL * DD;

    __shared__ h1 Albuf[4*256*32];       // 64 KB: 4 slots x 16 KB
    __shared__ h1 Blbuf[4*256*32];       // 64 KB
    const int SLOT_H = 256*32;
    const int SLOT_B = SLOT_H*2;

    const int tid  = threadIdx.x;
    const int lane = tid & 63;
    const int wid  = tid >> 6;           // 0..7
    const int wm = wid >> 2;             // 0..1 (row half: 128 rows)
    const int wn = wid & 3;              // 0..3 (col quarter: 64 cols)
    const int g  = lane >> 4, c = lane & 15;

    f32x4 acc[8][4];
    #pragma unroll
    for (int i = 0; i < 8; i++)
        #pragma unroll
        for (int j = 0; j < 4; j++) acc[i][j] = (f32x4){0.f, 0.f, 0.f, 0.f};

    // prologue: stage K-steps 0,1,2 into slots 0,1,2
    #pragma unroll
    for (int kt = 0; kt < 3; ++kt) {
        stage_slot32(Qb + (size_t)m0*DD + kt*32, (char*)Albuf + kt*SLOT_B, wid, lane);
        stage_slot32(Kb + (size_t)n0*DD + kt*32, (char*)Blbuf + kt*SLOT_B, wid, lane);
    }
    asm volatile("s_waitcnt vmcnt(8)" ::: "memory");   // slot 0 ready
    __builtin_amdgcn_s_barrier();

    for (int kt = 0; kt < 16; ++kt) {
        const int cur = kt & 3;
        const h1* Abase = Albuf + cur*SLOT_H;
        const h1* Bbase = Blbuf + cur*SLOT_H;

        // ---- phase A: af(mh=0) + bf reads; prefetch slot kt+3; 16 MFMA ----
        h8 af[4], bf[4];
        #pragma unroll
        for (int fm = 0; fm < 4; fm++) af[fm] = frag32(Abase, wm*128 + fm*16 + c, g);
        #pragma unroll
        for (int fn = 0; fn < 4; fn++) bf[fn] = frag32(Bbase, wn*64 + fn*16 + c, g);

        if (kt <= 12) {
            const int nk = kt + 3, ns = nk & 3;
            stage_slot32(Qb + (size_t)m0*DD + nk*32, (char*)Albuf + ns*SLOT_B, wid, lane);
            stage_slot32(Kb + (size_t)n0*DD + nk*32, (char*)Blbuf + ns*SLOT_B, wid, lane);
        }

        __builtin_amdgcn_s_barrier();
        asm volatile("s_waitcnt lgkmcnt(0)" ::: "memory");
        __builtin_amdgcn_sched_barrier(0);
        __builtin_amdgcn_s_setprio(1);
        #pragma unroll
        for (int fm = 0; fm < 4; fm++)
            #pragma unroll
            for (int fn = 0; fn < 4; fn++)
                acc[fm][fn] = __builtin_amdgcn_mfma_f32_16x16x32_f16(af[fm], bf[fn], acc[fm][fn], 0, 0, 0);
        __builtin_amdgcn_s_setprio(0);
        __builtin_amdgcn_s_barrier();

        // ---- phase B: af(mh=1) reads; 16 MFMA; counted vmcnt; barrier ----
        #pragma unroll
        for (int fm = 0; fm < 4; fm++) af[fm] = frag32(Abase, wm*128 + 64 + fm*16 + c, g);

        __builtin_amdgcn_s_barrier();
        asm volatile("s_waitcnt lgkmcnt(0)" ::: "memory");
        __builtin_amdgcn_sched_barrier(0);
        __builtin_amdgcn_s_setprio(1);
        #pragma unroll
        for (int fm = 0; fm < 4; fm++)
            #pragma unroll
            for (int fn = 0; fn < 4; fn++)
                acc[4+fm][fn] = __builtin_amdgcn_mfma_f32_16x16x32_f16(af[fm], bf[fn], acc[4+fm][fn], 0, 0, 0);
        __builtin_amdgcn_s_setprio(0);

        // next slot must be resident before its phase-A reads; keep newer loads in flight
        if (kt <= 12)      { asm volatile("s_waitcnt vmcnt(8)" ::: "memory"); }
        else if (kt == 13) { asm volatile("s_waitcnt vmcnt(4)" ::: "memory"); }
        else if (kt == 14) { asm volatile("s_waitcnt vmcnt(0)" ::: "memory"); }
        __builtin_amdgcn_s_barrier();
    }

    // epilogue: exp + fp16 store + per-row partial sums
    const float inv_scale = 0.08838834764831845f;   // 1/sqrt(128)
    #pragma unroll
    for (int mf = 0; mf < 8; mf++) {
        #pragma unroll
        for (int i = 0; i < 4; i++) {
            const int row = m0 + wm*128 + mf*16 + g*4 + i;
            h1* erow = Eh + ((size_t)b * SL + row) * SL;
            float rsum = 0.f;
            #pragma unroll
            for (int nf = 0; nf < 4; nf++) {
                const int col = n0 + wn*64 + nf*16 + c;
                float e = __expf(fmaf(acc[mf][nf][i], inv_scale, -SHIFT));
                erow[col] = (h1)e;
                rsum += e;
            }
            #pragma unroll
            for (int off = 1; off < 16; off <<= 1) rsum += __shfl_xor(rsum, off);
            if (c == 0)
                partial[((size_t)b * SL + row) * 64 + tx * 4 + wn] = rsum;
        }
    }
}

// ---------------- K2b: rowsum -> reciprocal ----------------
__global__ __launch_bounds__(256) void rowsum_inv(
    const float* __restrict__ partial, float* __restrict__ invrow)
{
    int row = blockIdx.x * 256 + threadIdx.x;   // 0..MM-1
    const f4* p = (const f4*)(partial + (size_t)row * 64);
    float s = 0.f;
    #pragma unroll
    for (int i = 0; i < 16; i++) { f4 v = p[i]; s += v[0] + v[1] + v[2] + v[3]; }
    invrow[row] = 1.0f / s;
}

// ---------------- K3: weights = fp16 e * invrow -> f32 out ----------------
__global__ __launch_bounds__(256) void normalize_k(
    const h1* __restrict__ Eh, const float* __restrict__ invrow,
    float* __restrict__ Wout)
{
    const size_t total8 = (size_t)NB * SL * SL / 8;     // h8 count
    size_t i = (size_t)blockIdx.x * blockDim.x + threadIdx.x;
    const size_t stride = (size_t)gridDim.x * blockDim.x;
    for (; i < total8; i += stride) {
        const int row = (int)(i >> 9);                  // 512 h8 per 4096-col row
        h8 v = ((const h8*)Eh)[i];
        const float s = invrow[row];
        f4 o0, o1;
        #pragma unroll
        for (int j = 0; j < 4; j++) { o0[j] = (float)v[j] * s; o1[j] = (float)v[4+j] * s; }
        ((f4*)Wout)[i*2]   = o0;
        ((f4*)Wout)[i*2+1] = o1;
    }
}

extern "C" void kernel_launch(void* const* d_in, const int* in_sizes, int n_in,
                              void* d_out, int out_size, void* d_ws, size_t ws_size,
                              hipStream_t stream)
{
    const float* q  = (const float*)d_in[0];
    const float* k  = (const float*)d_in[1];
    const float* v  = (const float*)d_in[2];
    const float* Wq = (const float*)d_in[3];
    const float* bq = (const float*)d_in[4];
    const float* Wk = (const float*)d_in[5];
    const float* bk = (const float*)d_in[6];
    const float* Wv = (const float*)d_in[7];
    const float* bv = (const float*)d_in[8];

    float* out  = (float*)d_out;
    float* Vout = out;                                 // [NB,SL,DD] f32 (output 0 == V)
    float* Wout = out + (size_t)MM * DD;               // [NB,SL,SL] weights

    char* ws = (char*)d_ws;
    h1* Xh = (h1*)ws;                                              // 48 MB
    h1* Wh = (h1*)(ws + (size_t)3*MM*DD*2);                        // 1.5 MB
    h1* Qh = (h1*)((char*)Wh + (size_t)3*DD*DD*2);                 // 16 MB
    h1* Kh = (h1*)((char*)Qh + (size_t)MM*DD*2);                   // 16 MB
    float* partial = (float*)((char*)Kh + (size_t)MM*DD*2);        // 4 MB
    float* invrow  = (float*)((char*)partial + (size_t)MM*64*4);   // 64 KB
    h1* Eh = (h1*)((char*)invrow + (size_t)MM*4);                  // 134 MB

    const int conv_chunks = (3*MM*DD + 3*DD*DD) / 4;
    convert_all<<<(conv_chunks + 255)/256, 256, 0, stream>>>(q, k, v, Wq, Wk, Wv, Xh, Wh);
    proj_gemm<<<dim3(4, 128, 3), 256, 0, stream>>>(Xh, Wh, bq, bk, bv, Qh, Kh, Vout);
    scores_gemm_8ph<<<1024, 512, 0, stream>>>(Qh, Kh, Eh, partial);
    rowsum_inv<<<MM / 256, 256, 0, stream>>>(partial, invrow);
    normalize_k<<<2048, 256, 0, stream>>>(Eh, invrow, Wout);
}